// Round 8
// baseline (239.256 us; speedup 1.0000x reference)
//
#include <hip/hip_runtime.h>
#include <hip/hip_cooperative_groups.h>
#include <math.h>

namespace cg = cooperative_groups;

#define BB 8
#define CC 64
#define NN 4096
#define CI 8
#define GAMMA 0.1f
// exp(s/sqrt(8)) = exp2(s * log2(e)/sqrt(8)); folded into k in phase 1.
#define SCALE (1.44269504088896f * 0.35355339059327f)
#define NSPLIT 4

typedef float v4f __attribute__((ext_vector_type(4)));
typedef __bf16 bf16x8 __attribute__((ext_vector_type(8)));
typedef __bf16 bf16x4 __attribute__((ext_vector_type(4)));

__device__ __forceinline__ float fast_exp2(float x) {
    return __builtin_amdgcn_exp2f(x);
}

// ONE cooperative kernel (R6 retry, WITHOUT the launch_bounds spill own-goal).
// R1..R7 evidence: residual ≈ 23us per dispatch x3. Phase bodies are the
// R7-proven math (absmax 0.0156); att phase re-pipelined:
//   - unroll-2, two per-wave LDS buffers, no barriers in the n-loop
//     -> two MFMA->exp->LDS->MFMA chains in flight per wave
//   - LDS ops per chunk 10 -> 3 (2x ds_write_b64 + 1x ds_read_b128,
//     80B row pitch: 16B-aligned, worst 2-way conflicts = free)
__global__ __launch_bounds__(256) void fused_kernel(
        const float* __restrict__ x,
        const float* __restrict__ Wq, const float* __restrict__ Wk,
        const float* __restrict__ Wv, const float* __restrict__ Wout,
        __bf16* __restrict__ qbh, __bf16* __restrict__ kbh,
        __bf16* __restrict__ vbh, float* __restrict__ attab,
        float* __restrict__ out) {
    __shared__ __align__(16) char smem[10240];
    cg::grid_group grid = cg::this_grid();
    const int t = threadIdx.x;
    const int nblk = gridDim.x;

    // ================= phase 1: qkv (bf16 out) + zero attab =================
    {
        float* sw = (float*)smem;                             // 1536 floats
        unsigned short* sq = (unsigned short*)(smem + 6144);  // [32][8]
        unsigned short* sk = sq + 256;
        for (int idx = blockIdx.x * 256 + t; idx < BB * 9 * NN; idx += nblk * 256)
            attab[idx] = 0.f;
        for (int idx = t; idx < CI * CC; idx += 256) {
            sw[idx]        = Wq[idx];
            sw[512 + idx]  = Wk[idx] * SCALE;
            sw[1024 + idx] = Wv[idx];
        }
        __syncthreads();
        const int i  = t >> 5;       // 0..7
        const int nl = t & 31;       // 0..31
        for (int tile = blockIdx.x; tile < BB * (NN / 32); tile += nblk) {
            const int b  = tile >> 7;
            const int n0 = (tile & 127) * 32;
            const int n  = n0 + nl;
            const float* xp = x + ((size_t)b * CC) * NN + n;
            const v4f* wq4 = (const v4f*)(sw + i * CC);
            const v4f* wk4 = (const v4f*)(sw + 512 + i * CC);
            const v4f* wv4 = (const v4f*)(sw + 1024 + i * CC);
            float qa = 0.f, ka = 0.f, va = 0.f;
#pragma unroll 4
            for (int c4 = 0; c4 < CC / 4; ++c4) {
                v4f wq = wq4[c4], wk = wk4[c4], wv = wv4[c4];   // LDS broadcast
                float x0 = xp[(size_t)(c4 * 4 + 0) * NN];
                float x1 = xp[(size_t)(c4 * 4 + 1) * NN];
                float x2 = xp[(size_t)(c4 * 4 + 2) * NN];
                float x3 = xp[(size_t)(c4 * 4 + 3) * NN];
                qa = fmaf(wq.x, x0, qa); ka = fmaf(wk.x, x0, ka); va = fmaf(wv.x, x0, va);
                qa = fmaf(wq.y, x1, qa); ka = fmaf(wk.y, x1, ka); va = fmaf(wv.y, x1, va);
                qa = fmaf(wq.z, x2, qa); ka = fmaf(wk.z, x2, ka); va = fmaf(wv.z, x2, va);
                qa = fmaf(wq.w, x3, qa); ka = fmaf(wk.w, x3, ka); va = fmaf(wv.w, x3, va);
            }
            __bf16 vb = (__bf16)va;
            vbh[((size_t)b * CI + i) * NN + n] = vb;            // coalesced
            __bf16 qb = (__bf16)qa, kb2 = (__bf16)ka;
            sq[nl * 8 + i] = *(unsigned short*)&qb;
            sk[nl * 8 + i] = *(unsigned short*)&kb2;
            __syncthreads();
            if (t < 32) {
                *(uint4*)(qbh + ((size_t)b * NN + n0 + t) * 8) = *(const uint4*)(sq + t * 8);
                *(uint4*)(kbh + ((size_t)b * NN + n0 + t) * 8) = *(const uint4*)(sk + t * 8);
            }
            __syncthreads();
        }
    }
    grid.sync();

    // ================= phase 2: MFMA attention =================
    // |scores| < ~2 -> exp without max-subtraction safe (shift-invariant).
    // Unit u in [0,2048): b = u>>8, ns = (u>>6)&3, mb = u&63.
    // Per wave: 16-m tile; S via 2x mfma_16x16x32_bf16 (k<8 live);
    // E -> per-wave LDS transpose -> B-frag; PV with A=[v0..v7; ones; 0..]
    // (ones row = denominator for free). attab[b][9][N] += via fp32 atomics.
    {
        const int w    = t >> 6;
        const int l    = t & 63;
        const int quad = l >> 4;
        const int lm   = l & 15;
        unsigned short* buf0 = (unsigned short*)smem + w * 1280;  // [16][40]
        unsigned short* buf1 = buf0 + 640;

        bf16x8 zero8, ones8;
#pragma unroll
        for (int z = 0; z < 8; ++z) { zero8[z] = (__bf16)0.0f; ones8[z] = (__bf16)1.0f; }

        for (int u = blockIdx.x; u < BB * NSPLIT * (NN / 64); u += nblk) {
            const int b     = u >> 8;
            const int nbase = ((u >> 6) & (NSPLIT - 1)) * (NN / NSPLIT);
            const int m0    = (u & 63) * 64 + w * 16;

            bf16x8 kfrag = zero8;
            if (quad == 0)
                kfrag = *(const bf16x8*)(kbh + ((size_t)b * NN + m0 + lm) * 8);
            const __bf16* vrow = vbh + ((size_t)b * CI + (lm & 7)) * NN;
            const __bf16* qrow = qbh + (size_t)b * NN * 8;

            v4f accO = {0.f, 0.f, 0.f, 0.f};

            auto stage1 = [&](int nc, unsigned short* buf, bf16x8& vfrag) {
                bf16x8 q0 = zero8, q1 = zero8;
                if (quad == 0) {
                    q0 = *(const bf16x8*)(qrow + (size_t)(nc + lm) * 8);
                    q1 = *(const bf16x8*)(qrow + (size_t)(nc + 16 + lm) * 8);
                }
                if (lm < 8)       vfrag = *(const bf16x8*)(vrow + nc + quad * 8);
                else if (lm == 8) vfrag = ones8;
                else              vfrag = zero8;
                v4f s0 = __builtin_amdgcn_mfma_f32_16x16x32_bf16(q0, kfrag, (v4f){0.f,0.f,0.f,0.f}, 0, 0, 0);
                v4f s1 = __builtin_amdgcn_mfma_f32_16x16x32_bf16(q1, kfrag, (v4f){0.f,0.f,0.f,0.f}, 0, 0, 0);
                bf16x4 e0, e1;
                e0[0] = (__bf16)fast_exp2(s0.x); e0[1] = (__bf16)fast_exp2(s0.y);
                e0[2] = (__bf16)fast_exp2(s0.z); e0[3] = (__bf16)fast_exp2(s0.w);
                e1[0] = (__bf16)fast_exp2(s1.x); e1[1] = (__bf16)fast_exp2(s1.y);
                e1[2] = (__bf16)fast_exp2(s1.z); e1[3] = (__bf16)fast_exp2(s1.w);
                // buf[m=lm][n_rel]: rows 80B; e0 -> n_rel quad*4.., e1 -> 16+quad*4..
                *(bf16x4*)(buf + lm * 40 + quad * 4)      = e0;   // ds_write_b64
                *(bf16x4*)(buf + lm * 40 + 16 + quad * 4) = e1;
            };
            auto stage2 = [&](unsigned short* buf, bf16x8 vfrag) {
                // B[k=quad*8+j][col=lm] = buf[lm][quad*8+j]; 16B aligned read
                bf16x8 efrag = *(const bf16x8*)(buf + lm * 40 + quad * 8);
                accO = __builtin_amdgcn_mfma_f32_16x16x32_bf16(vfrag, efrag, accO, 0, 0, 0);
            };

            for (int ch = 0; ch < (NN / NSPLIT) / 32; ch += 2) {
                bf16x8 vf0, vf1;
                stage1(nbase + ch * 32, buf0, vf0);
                stage1(nbase + (ch + 1) * 32, buf1, vf1);
                stage2(buf0, vf0);
                stage2(buf1, vf1);
            }

            // D[row=quad*4+r][col=lm]; rows 0..7 = sum e*v_i, row 8 = sum e.
            float* ap = attab + (size_t)b * 9 * NN + m0 + lm;
            float av[4] = {accO.x, accO.y, accO.z, accO.w};
#pragma unroll
            for (int r = 0; r < 4; ++r) {
                int i = quad * 4 + r;
                if (i < 9) atomicAdd(ap + (size_t)i * NN, av[r]);
            }
        }
    }
    grid.sync();

    // ================= phase 3: out projection + residual =================
    for (int q = blockIdx.x * 256 + t; q < BB * CC * (NN / 4); q += nblk * 256) {
        const int m4   = q & (NN / 4 - 1);
        const int rest = q >> 10;
        const int c = rest & (CC - 1);
        const int b = rest >> 6;
        const int m = m4 * 4;
        const float* ap = attab + (size_t)b * 9 * NN + m;
        v4f sum = *(const v4f*)(ap + (size_t)8 * NN);
        v4f s = {0.f, 0.f, 0.f, 0.f};
#pragma unroll
        for (int i = 0; i < CI; ++i) {
            float wgt = Wout[c * CI + i];
            v4f a = *(const v4f*)(ap + (size_t)i * NN);
            s.x = fmaf(wgt, a.x, s.x);
            s.y = fmaf(wgt, a.y, s.y);
            s.z = fmaf(wgt, a.z, s.z);
            s.w = fmaf(wgt, a.w, s.w);
        }
        size_t o = ((size_t)b * CC + c) * NN + m;
        v4f xv = *(const v4f*)(x + o);
        v4f r;
        r.x = xv.x + GAMMA * (s.x / sum.x);
        r.y = xv.y + GAMMA * (s.y / sum.y);
        r.z = xv.z + GAMMA * (s.z / sum.z);
        r.w = xv.w + GAMMA * (s.w / sum.w);
        *(v4f*)(out + o) = r;
    }
}

extern "C" void kernel_launch(void* const* d_in, const int* in_sizes, int n_in,
                              void* d_out, int out_size, void* d_ws, size_t ws_size,
                              hipStream_t stream) {
    const float* x    = (const float*)d_in[0];
    const float* Wq   = (const float*)d_in[1];
    const float* Wk   = (const float*)d_in[2];
    const float* Wv   = (const float*)d_in[3];
    const float* Wout = (const float*)d_in[4];
    float* out = (float*)d_out;

    // ws: qbh [B][N][8] bf16 | kbh [B][N][8] bf16 | vbh [B][8][N] bf16 |
    //     attab [B][9][N] fp32
    __bf16* qbh = (__bf16*)d_ws;
    __bf16* kbh = qbh + (size_t)BB * NN * 8;
    __bf16* vbh = kbh + (size_t)BB * NN * 8;
    float* attab = (float*)(vbh + (size_t)BB * NN * 8);

    int occ = 0;
    hipOccupancyMaxActiveBlocksPerMultiprocessor(&occ, fused_kernel, 256, 0);
    if (occ < 1) occ = 1;
    int gridn = occ * 256;            // 256 CUs
    if (gridn > 2048) gridn = 2048;

    void* args[] = {(void*)&x, (void*)&Wq, (void*)&Wk, (void*)&Wv, (void*)&Wout,
                    (void*)&qbh, (void*)&kbh, (void*)&vbh, (void*)&attab, (void*)&out};
    hipLaunchCooperativeKernel((const void*)fused_kernel, dim3(gridn), dim3(256),
                               args, 0, stream);
}

// Round 9
// 113.805 us; speedup vs baseline: 2.1023x; 2.1023x over previous
//
#include <hip/hip_runtime.h>
#include <math.h>

#define BB 8
#define CC 64
#define NN 4096
#define CI 8
#define GAMMA 0.1f
// exp(s/sqrt(8)) = exp2(s * log2(e)/sqrt(8)); folded into k in qkv.
#define SCALE (1.44269504088896f * 0.35355339059327f)
#define NSPLIT 4

typedef float v4f __attribute__((ext_vector_type(4)));
typedef __bf16 bf16x8 __attribute__((ext_vector_type(8)));
typedef __bf16 bf16x4 __attribute__((ext_vector_type(4)));

__device__ __forceinline__ float fast_exp2(float x) {
    return __builtin_amdgcn_exp2f(x);
}

// R7-proven qkv. Grid (NN/32, BB); block 256 = 8 i-groups x 32 n.
// qbh[b][n][8], kbh[b][m][8] (k*SCALE), vbh[b][i][N]; zeros attab[b][9][N].
__global__ __launch_bounds__(256) void qkv_kernel(
        const float* __restrict__ x,
        const float* __restrict__ Wq, const float* __restrict__ Wk,
        const float* __restrict__ Wv,
        __bf16* __restrict__ qbh, __bf16* __restrict__ kbh,
        __bf16* __restrict__ vbh, float* __restrict__ attab) {
    __shared__ float sw[3 * CI * CC];     // 6 KB: Wq | Wk*SCALE | Wv
    __shared__ unsigned short sq[32 * 8]; // bf16 tile [n_local][i]
    __shared__ unsigned short sk[32 * 8];
    const int t = threadIdx.x;
    const int i  = t >> 5;
    const int nl = t & 31;
    const int b  = blockIdx.y;
    const int n0 = blockIdx.x * 32;

    for (int idx = t; idx < CI * CC; idx += 256) {
        sw[idx]                = Wq[idx];
        sw[CI * CC + idx]      = Wk[idx] * SCALE;
        sw[2 * CI * CC + idx]  = Wv[idx];
    }
    int lin = (blockIdx.y * (NN / 32) + blockIdx.x) * 256 + t;
    for (int idx = lin; idx < BB * 9 * NN; idx += BB * NN * CI) attab[idx] = 0.f;
    __syncthreads();

    const int n = n0 + nl;
    const float* xp = x + ((size_t)b * CC) * NN + n;
    const v4f* wq4 = (const v4f*)(sw + i * CC);
    const v4f* wk4 = (const v4f*)(sw + CI * CC + i * CC);
    const v4f* wv4 = (const v4f*)(sw + 2 * CI * CC + i * CC);
    float qa = 0.f, ka = 0.f, va = 0.f;
#pragma unroll 4
    for (int c4 = 0; c4 < CC / 4; ++c4) {
        v4f wq = wq4[c4], wk = wk4[c4], wv = wv4[c4];   // LDS broadcast b128
        float x0 = xp[(size_t)(c4 * 4 + 0) * NN];
        float x1 = xp[(size_t)(c4 * 4 + 1) * NN];
        float x2 = xp[(size_t)(c4 * 4 + 2) * NN];
        float x3 = xp[(size_t)(c4 * 4 + 3) * NN];
        qa = fmaf(wq.x, x0, qa); ka = fmaf(wk.x, x0, ka); va = fmaf(wv.x, x0, va);
        qa = fmaf(wq.y, x1, qa); ka = fmaf(wk.y, x1, ka); va = fmaf(wv.y, x1, va);
        qa = fmaf(wq.z, x2, qa); ka = fmaf(wk.z, x2, ka); va = fmaf(wv.z, x2, va);
        qa = fmaf(wq.w, x3, qa); ka = fmaf(wk.w, x3, ka); va = fmaf(wv.w, x3, va);
    }
    __bf16 vb = (__bf16)va;
    vbh[((size_t)b * CI + i) * NN + n] = vb;
    __bf16 qb = (__bf16)qa, kb2 = (__bf16)ka;
    sq[nl * 8 + i] = *(unsigned short*)&qb;
    sk[nl * 8 + i] = *(unsigned short*)&kb2;
    __syncthreads();
    if (t < 32) {
        *(uint4*)(qbh + ((size_t)b * NN + n0 + t) * 8) = *(const uint4*)(sq + t * 8);
        *(uint4*)(kbh + ((size_t)b * NN + n0 + t) * 8) = *(const uint4*)(sk + t * 8);
    }
}

// MFMA attention, R7 structure + TWO independent chains per wave.
// R7 PMC: MfmaUtil 11%, VALUBusy 41% -> one serial MFMA->exp->LDS->MFMA
// chain per wave, latency-bound. Each wave now processes the two halves of
// its n-range in lockstep with two private LDS buffers (72B pitch — the
// pitch measured at ZERO bank conflicts in R7; R8's 80B pitch gave 3.2M)
// and two accumulators, summed before the epilogue.
// Grid (64 m-blocks, NSPLIT, BB) = 2048 blocks x 4 waves. LDS 9216B.
__global__ __launch_bounds__(256) void att_kernel(
        const __bf16* __restrict__ qbh, const __bf16* __restrict__ kbh,
        const __bf16* __restrict__ vbh, float* __restrict__ attab) {
    __shared__ unsigned short eld[4][2][16 * 36];  // per-wave dual transpose bufs
    const int t = threadIdx.x;
    const int w    = t >> 6;
    const int l    = t & 63;
    const int quad = l >> 4;
    const int lm   = l & 15;
    const int b  = blockIdx.z;
    const int m0 = blockIdx.x * 64 + w * 16;
    const int nbase = blockIdx.y * (NN / NSPLIT);
    const int HALF = (NN / NSPLIT) / 2;            // 512

    bf16x8 zero8, ones8;
#pragma unroll
    for (int z = 0; z < 8; ++z) { zero8[z] = (__bf16)0.0f; ones8[z] = (__bf16)1.0f; }

    bf16x8 kfrag = zero8;                          // shared by both chains
    if (quad == 0)
        kfrag = *(const bf16x8*)(kbh + ((size_t)b * NN + m0 + lm) * 8);

    const __bf16* vrow = vbh + ((size_t)b * CI + (lm & 7)) * NN;
    const __bf16* qrow = qbh + (size_t)b * NN * 8;

    v4f acc0 = {0.f, 0.f, 0.f, 0.f};
    v4f acc1 = {0.f, 0.f, 0.f, 0.f};
    unsigned short* ew0 = &eld[w][0][lm * 36];
    unsigned short* ew1 = &eld[w][1][lm * 36];

    for (int ch = 0; ch < HALF / 32; ++ch) {
        const int nc0 = nbase + ch * 32;
        const int nc1 = nc0 + HALF;

        // ---- chain 0, stage 1 ----
        bf16x8 a_q0 = zero8, a_q1 = zero8;
        if (quad == 0) {
            a_q0 = *(const bf16x8*)(qrow + (size_t)(nc0 + lm) * 8);
            a_q1 = *(const bf16x8*)(qrow + (size_t)(nc0 + 16 + lm) * 8);
        }
        bf16x8 vf0;
        if (lm < 8)       vf0 = *(const bf16x8*)(vrow + nc0 + quad * 8);
        else if (lm == 8) vf0 = ones8;
        else              vf0 = zero8;
        v4f a_s0 = __builtin_amdgcn_mfma_f32_16x16x32_bf16(a_q0, kfrag, (v4f){0.f,0.f,0.f,0.f}, 0, 0, 0);
        v4f a_s1 = __builtin_amdgcn_mfma_f32_16x16x32_bf16(a_q1, kfrag, (v4f){0.f,0.f,0.f,0.f}, 0, 0, 0);

        // ---- chain 1, stage 1 ----
        bf16x8 b_q0 = zero8, b_q1 = zero8;
        if (quad == 0) {
            b_q0 = *(const bf16x8*)(qrow + (size_t)(nc1 + lm) * 8);
            b_q1 = *(const bf16x8*)(qrow + (size_t)(nc1 + 16 + lm) * 8);
        }
        bf16x8 vf1;
        if (lm < 8)       vf1 = *(const bf16x8*)(vrow + nc1 + quad * 8);
        else if (lm == 8) vf1 = ones8;
        else              vf1 = zero8;
        v4f b_s0 = __builtin_amdgcn_mfma_f32_16x16x32_bf16(b_q0, kfrag, (v4f){0.f,0.f,0.f,0.f}, 0, 0, 0);
        v4f b_s1 = __builtin_amdgcn_mfma_f32_16x16x32_bf16(b_q1, kfrag, (v4f){0.f,0.f,0.f,0.f}, 0, 0, 0);

        // ---- chain 0: exp -> bf16 -> LDS (72B-pitch rows, b64 writes) ----
        bf16x4 e;
        e[0] = (__bf16)fast_exp2(a_s0.x); e[1] = (__bf16)fast_exp2(a_s0.y);
        e[2] = (__bf16)fast_exp2(a_s0.z); e[3] = (__bf16)fast_exp2(a_s0.w);
        *(bf16x4*)(ew0 + quad * 4) = e;
        e[0] = (__bf16)fast_exp2(a_s1.x); e[1] = (__bf16)fast_exp2(a_s1.y);
        e[2] = (__bf16)fast_exp2(a_s1.z); e[3] = (__bf16)fast_exp2(a_s1.w);
        *(bf16x4*)(ew0 + 16 + quad * 4) = e;

        // ---- chain 1: exp -> bf16 -> LDS ----
        e[0] = (__bf16)fast_exp2(b_s0.x); e[1] = (__bf16)fast_exp2(b_s0.y);
        e[2] = (__bf16)fast_exp2(b_s0.z); e[3] = (__bf16)fast_exp2(b_s0.w);
        *(bf16x4*)(ew1 + quad * 4) = e;
        e[0] = (__bf16)fast_exp2(b_s1.x); e[1] = (__bf16)fast_exp2(b_s1.y);
        e[2] = (__bf16)fast_exp2(b_s1.z); e[3] = (__bf16)fast_exp2(b_s1.w);
        *(bf16x4*)(ew1 + 16 + quad * 4) = e;

        // ---- stage 2 (both chains): read E as B-frag, PV MFMA ----
        {
            bf16x4 lo = *(const bf16x4*)(ew0 + quad * 8);
            bf16x4 hi = *(const bf16x4*)(ew0 + quad * 8 + 4);
            bf16x8 ef;
#pragma unroll
            for (int z = 0; z < 4; ++z) { ef[z] = lo[z]; ef[4 + z] = hi[z]; }
            acc0 = __builtin_amdgcn_mfma_f32_16x16x32_bf16(vf0, ef, acc0, 0, 0, 0);
        }
        {
            bf16x4 lo = *(const bf16x4*)(ew1 + quad * 8);
            bf16x4 hi = *(const bf16x4*)(ew1 + quad * 8 + 4);
            bf16x8 ef;
#pragma unroll
            for (int z = 0; z < 4; ++z) { ef[z] = lo[z]; ef[4 + z] = hi[z]; }
            acc1 = __builtin_amdgcn_mfma_f32_16x16x32_bf16(vf1, ef, acc1, 0, 0, 0);
        }
    }

    // Epilogue: D[row=quad*4+r][col=lm]; rows 0..7 = sum e*v_i, row 8 = sum e.
    v4f accO = {acc0.x + acc1.x, acc0.y + acc1.y, acc0.z + acc1.z, acc0.w + acc1.w};
    float* ap = attab + (size_t)b * 9 * NN + m0 + lm;
    float av[4] = {accO.x, accO.y, accO.z, accO.w};
#pragma unroll
    for (int r = 0; r < 4; ++r) {
        int i = quad * 4 + r;
        if (i < 9) atomicAdd(ap + (size_t)i * NN, av[r]);
    }
}

// R7-proven out. Grid (NN/1024, CC, BB); block 256; float4 per thread.
__global__ __launch_bounds__(256) void out_kernel(
        const float* __restrict__ x, const float* __restrict__ Wout,
        const float* __restrict__ attab, float* __restrict__ out) {
    const int t = threadIdx.x;
    const int c = blockIdx.y;
    const int b = blockIdx.z;
    const int m = (blockIdx.x * 256 + t) * 4;
    const float* ap = attab + (size_t)b * 9 * NN + m;
    v4f sum = *(const v4f*)(ap + (size_t)8 * NN);
    v4f s = {0.f, 0.f, 0.f, 0.f};
#pragma unroll
    for (int i = 0; i < CI; ++i) {
        float wgt = Wout[c * CI + i];               // uniform -> s_load
        v4f a = *(const v4f*)(ap + (size_t)i * NN);
        s.x = fmaf(wgt, a.x, s.x);
        s.y = fmaf(wgt, a.y, s.y);
        s.z = fmaf(wgt, a.z, s.z);
        s.w = fmaf(wgt, a.w, s.w);
    }
    size_t o = ((size_t)b * CC + c) * NN + m;
    v4f xv = *(const v4f*)(x + o);
    v4f r;
    r.x = xv.x + GAMMA * (s.x / sum.x);
    r.y = xv.y + GAMMA * (s.y / sum.y);
    r.z = xv.z + GAMMA * (s.z / sum.z);
    r.w = xv.w + GAMMA * (s.w / sum.w);
    *(v4f*)(out + o) = r;
}

extern "C" void kernel_launch(void* const* d_in, const int* in_sizes, int n_in,
                              void* d_out, int out_size, void* d_ws, size_t ws_size,
                              hipStream_t stream) {
    const float* x    = (const float*)d_in[0];
    const float* Wq   = (const float*)d_in[1];
    const float* Wk   = (const float*)d_in[2];
    const float* Wv   = (const float*)d_in[3];
    const float* Wout = (const float*)d_in[4];
    float* out = (float*)d_out;

    // ws: qbh [B][N][8] bf16 | kbh [B][N][8] bf16 | vbh [B][8][N] bf16 |
    //     attab [B][9][N] fp32
    __bf16* qbh = (__bf16*)d_ws;
    __bf16* kbh = qbh + (size_t)BB * NN * 8;
    __bf16* vbh = kbh + (size_t)BB * NN * 8;
    float* attab = (float*)(vbh + (size_t)BB * NN * 8);

    qkv_kernel<<<dim3(NN / 32, BB), 256, 0, stream>>>(x, Wq, Wk, Wv, qbh, kbh, vbh, attab);
    att_kernel<<<dim3(NN / 64, NSPLIT, BB), 256, 0, stream>>>(qbh, kbh, vbh, attab);
    out_kernel<<<dim3(NN / 1024, CC, BB), 256, 0, stream>>>(x, Wout, attab, out);
}